// Round 6
// baseline (989.254 us; speedup 1.0000x reference)
//
#include <hip/hip_runtime.h>

#define D_     784
#define ROWS   8
#define NCLS   10
#define BLOCK  768              // 12 waves; 2 persistent blocks/CU = 24 waves
#define CPB    512              // persistent grid: 2 blocks x 256 CU
#define NB     (65536 / ROWS)   // 8192 row-groups
#define NITER  (NB / CPB)       // 16 row-groups per block
#define PL     (D_ * 4)         // floats per LDS plane (3136)
#define TAILN  16               // features 768..783

// tanh-approx GELU (|err| vs exact erf-GELU ~5e-4)
__device__ __forceinline__ float gelu_f(float x) {
    float x2    = x * x;
    float inner = fmaf(0.044715f * x, x2, x);
    float e     = exp2f(2.3022082f * inner);          // 2*sqrt(2/pi)*log2(e)
    float r     = __builtin_amdgcn_rcpf(e + 1.0f);
    return fmaf(-x, r, x);                            // x*e/(e+1)
}

__device__ __forceinline__ float4 gelu4(const float4& a) {
    return make_float4(gelu_f(a.x), gelu_f(a.y), gelu_f(a.z), gelu_f(a.w));
}

__device__ __forceinline__ void fma4(float4& a, const float4& h4, float wk) {
    a.x = fmaf(h4.x, wk, a.x);
    a.y = fmaf(h4.y, wk, a.y);
    a.z = fmaf(h4.z, wk, a.z);
    a.w = fmaf(h4.w, wk, a.w);
}

template <int K>
__device__ __forceinline__ void loadIdxW(const int* __restrict__ idx,
                                         const float* __restrict__ w,
                                         int n, int* jc, float* wc) {
    if constexpr (K == 2) {
        int2   j = *(const int2*)(idx + n * 2);
        float2 v = *(const float2*)(w + n * 2);
        jc[0] = j.x; jc[1] = j.y; wc[0] = v.x; wc[1] = v.y;
    } else if constexpr (K == 4) {
        int4   j = *(const int4*)(idx + n * 4);
        float4 v = *(const float4*)(w + n * 4);
        jc[0] = j.x; jc[1] = j.y; jc[2] = j.z; jc[3] = j.w;
        wc[0] = v.x; wc[1] = v.y; wc[2] = v.z; wc[3] = v.w;
    } else {
        int4   ja = *(const int4*)(idx + n * 8);
        int4   jb = *(const int4*)(idx + n * 8 + 4);
        float4 va = *(const float4*)(w + n * 8);
        float4 vb = *(const float4*)(w + n * 8 + 4);
        jc[0] = ja.x; jc[1] = ja.y; jc[2] = ja.z; jc[3] = ja.w;
        jc[4] = jb.x; jc[5] = jb.y; jc[6] = jb.z; jc[7] = jb.w;
        wc[0] = va.x; wc[1] = va.y; wc[2] = va.z; wc[3] = va.w;
        wc[4] = vb.x; wc[5] = vb.y; wc[6] = vb.z; wc[7] = vb.w;
    }
}

// Layer with register-cached idx/w/bias (const-indexed, fully unrolled -> stays in VGPRs)
template <int K>
__device__ __forceinline__ void layer_reg(const float* __restrict__ src,
                                          float* __restrict__ dst,
                                          const int (&jc)[K], const float (&wc)[K],
                                          float bc, int n) {
    float4 lo = make_float4(bc, bc, bc, bc);
    float4 hi = lo;
#pragma unroll
    for (int k = 0; k < K; ++k) {
        const float* g = src + jc[k] * 4;
        fma4(lo, *(const float4*)g, wc[k]);
        fma4(hi, *(const float4*)(g + PL), wc[k]);
    }
    *(float4*)(dst + n * 4)      = gelu4(lo);
    *(float4*)(dst + n * 4 + PL) = gelu4(hi);
}

// Layer with per-call reload (tail features; addresses identical every iter -> L1-hot)
template <int K>
__device__ __forceinline__ void layer_one(const float* __restrict__ src,
                                          float* __restrict__ dst,
                                          const int* __restrict__ idx,
                                          const float* __restrict__ w,
                                          const float* __restrict__ bias,
                                          int n) {
    int   jc[K];
    float wc[K];
    loadIdxW<K>(idx, w, n, jc, wc);
    layer_reg<K>(src, dst, jc, wc, bias[n], n);
}

__global__ __launch_bounds__(BLOCK, 6)   // min 6 waves/EU -> VGPR <= 85 -> 2 blocks/CU
void circnn_kernel(const float* __restrict__ x,
                   const int* __restrict__ idx1, const float* __restrict__ w1, const float* __restrict__ b1,
                   const int* __restrict__ idx2, const float* __restrict__ w2, const float* __restrict__ b2,
                   const int* __restrict__ idx3, const float* __restrict__ w3, const float* __restrict__ b3,
                   const float* __restrict__ fcw, const float* __restrict__ fcb,
                   float* __restrict__ out) {
    __shared__ __align__(16) float bufA[D_ * ROWS];       // 25,088 B: x, h2
    __shared__ __align__(16) float bufB[D_ * ROWS];       // 25,088 B: h1, h3
    __shared__ __align__(16) float partC[128 * NCLS * 4]; // 20,480 B: FC partials
    __shared__ float logits[ROWS * NCLS];                 // 320 B   -> total 70,976 B

    const int tid = threadIdx.x;

    // ---- one-time: cache idx/w/bias for main feature n = tid (31 VGPRs, reused 16x)
    int   j1[2], j2[4], j3[8];
    float v1[2], v2[4], v3[8];
    loadIdxW<2>(idx1, w1, tid, j1, v1);
    loadIdxW<4>(idx2, w2, tid, j2, v2);
    loadIdxW<8>(idx3, w3, tid, j3, v3);
    const float bb1 = b1[tid], bb2 = b2[tid], bb3 = b3[tid];

    const bool isTail = (tid >= BLOCK - TAILN);   // last 16 threads of wave 11
    const int  ntail  = tid + TAILN;              // feature 768..783

    // tail-x loader: threads 0..127 stage one value (feature 768+(tid>>3), row tid&7)
    const int xtN = 768 + (tid >> 3);
    const int xtR = tid & 7;

    // ---- prologue: stage x(it=0) -> bufA
    {
        const float* xb = x + (size_t)blockIdx.x * ROWS * D_;
        float r0 = xb[0 * D_ + tid], r1 = xb[1 * D_ + tid];
        float r2 = xb[2 * D_ + tid], r3 = xb[3 * D_ + tid];
        float r4 = xb[4 * D_ + tid], r5 = xb[5 * D_ + tid];
        float r6 = xb[6 * D_ + tid], r7 = xb[7 * D_ + tid];
        *(float4*)(bufA + tid * 4)      = make_float4(r0, r1, r2, r3);
        *(float4*)(bufA + tid * 4 + PL) = make_float4(r4, r5, r6, r7);
        if (tid < 128)
            bufA[xtN * 4 + (xtR & 3) + (xtR >> 2) * PL] = xb[xtR * D_ + xtN];
    }
    __syncthreads();

#pragma unroll 1
    for (int it = 0; it < NITER; ++it) {
        const size_t grp  = (size_t)it * CPB + blockIdx.x;    // row-group 0..8191
        // ---- prefetch next iteration's x (consumed ~3 phases later)
        float nx0, nx1, nx2, nx3, nx4, nx5, nx6, nx7, nxt;
        if (it + 1 < NITER) {
            const float* xb = x + ((size_t)(it + 1) * CPB + blockIdx.x) * ROWS * D_;
            nx0 = xb[0 * D_ + tid]; nx1 = xb[1 * D_ + tid];
            nx2 = xb[2 * D_ + tid]; nx3 = xb[3 * D_ + tid];
            nx4 = xb[4 * D_ + tid]; nx5 = xb[5 * D_ + tid];
            nx6 = xb[6 * D_ + tid]; nx7 = xb[7 * D_ + tid];
            nxt = (tid < 128) ? xb[xtR * D_ + xtN] : 0.f;
        }

        // ---- three sparse layers, ping-pong A->B->A->B
        layer_reg<2>(bufA, bufB, j1, v1, bb1, tid);
        if (isTail) layer_one<2>(bufA, bufB, idx1, w1, b1, ntail);
        __syncthreads();

        layer_reg<4>(bufB, bufA, j2, v2, bb2, tid);
        if (isTail) layer_one<4>(bufB, bufA, idx2, w2, b2, ntail);
        __syncthreads();

        layer_reg<8>(bufA, bufB, j3, v3, bb3, tid);
        if (isTail) layer_one<8>(bufA, bufB, idx3, w3, b3, ntail);
        __syncthreads();
        // bufA (h2) now dead -> stage next x into it, overlapped with FC
        if (it + 1 < NITER) {
            *(float4*)(bufA + tid * 4)      = make_float4(nx0, nx1, nx2, nx3);
            *(float4*)(bufA + tid * 4 + PL) = make_float4(nx4, nx5, nx6, nx7);
            if (tid < 128)
                bufA[xtN * 4 + (xtR & 3) + (xtR >> 2) * PL] = nxt;
        }

        // ---- FC phase A: 128 threads, facc in registers (member access only)
        float4* part4 = (float4*)partC;   // layout [(jj*2+qq)*NCLS + c]
        if (tid < 128) {
            const int jj = tid >> 1;      // 0..63
            const int qq = tid & 1;       // row half (plane)
            float4 facc[NCLS];
#pragma unroll
            for (int c = 0; c < NCLS; ++c) facc[c] = make_float4(0.f, 0.f, 0.f, 0.f);
#pragma unroll 1
            for (int i = 0; i < 13; ++i) {
                int n = jj + 64 * i;
                if (n < D_) {
                    float4 hv = *(const float4*)(bufB + qq * PL + n * 4);
#pragma unroll
                    for (int c = 0; c < NCLS; ++c)
                        fma4(facc[c], hv, fcw[c * D_ + n]);
                }
            }
#pragma unroll
            for (int c = 0; c < NCLS; ++c)
                part4[(jj * 2 + qq) * NCLS + c] = facc[c];
        }
        __syncthreads();

        // ---- FC phase B: 80 threads (r, c) sum 64 jj-partials -> logits
        if (tid < ROWS * NCLS) {
            int r = tid / NCLS, c = tid - r * NCLS;
            int qq = r >> 2, comp = r & 3;
            float s = fcb[c];
#pragma unroll 4
            for (int jj = 0; jj < 64; ++jj)
                s += partC[((jj * 2 + qq) * NCLS + c) * 4 + comp];
            logits[tid] = s;
        }
        __syncthreads();

        // ---- softmax + store; overlaps with next iteration's layer1 (disjoint buffers)
        if (tid < ROWS * NCLS) {
            int r = tid / NCLS;
            const float* lg = logits + r * NCLS;
            float m = lg[0];
#pragma unroll
            for (int c = 1; c < NCLS; ++c) m = fmaxf(m, lg[c]);
            float s = 0.f;
#pragma unroll
            for (int c = 0; c < NCLS; ++c) s += __expf(lg[c] - m);
            out[grp * ROWS * NCLS + tid] = __expf(logits[tid] - m) / s;
        }
        // no barrier: next layer1 touches bufA/bufB only; logits/partC rewritten
        // next iter only after 4 more barriers.
    }
}

extern "C" void kernel_launch(void* const* d_in, const int* in_sizes, int n_in,
                              void* d_out, int out_size, void* d_ws, size_t ws_size,
                              hipStream_t stream) {
    const float* x    = (const float*)d_in[0];
    const int*   idx1 = (const int*)d_in[1];
    const float* w1   = (const float*)d_in[2];
    const float* b1   = (const float*)d_in[3];
    const int*   idx2 = (const int*)d_in[4];
    const float* w2   = (const float*)d_in[5];
    const float* b2   = (const float*)d_in[6];
    const int*   idx3 = (const int*)d_in[7];
    const float* w3   = (const float*)d_in[8];
    const float* b3   = (const float*)d_in[9];
    const float* fcw  = (const float*)d_in[10];
    const float* fcb  = (const float*)d_in[11];
    float* out = (float*)d_out;

    circnn_kernel<<<dim3(CPB), dim3(BLOCK), 0, stream>>>(
        x, idx1, w1, b1, idx2, w2, b2, idx3, w3, b3, fcw, fcb, out);
}

// Round 8
// 563.985 us; speedup vs baseline: 1.7540x; 1.7540x over previous
//
#include <hip/hip_runtime.h>

#define D_     784
#define ROWS   8
#define NCLS   10
#define NCLSP  11               // padded FC-partial stride (float4s) to spread banks
#define BLOCK  768              // 12 waves; ~2 blocks/CU (proven best residency shape)
#define NB     (65536 / ROWS)   // 8192 blocks
#define PL     (D_ * 4)         // floats per LDS plane (3136): plane0 = rows 0-3, plane1 = rows 4-7
#define TAIL   (D_ - BLOCK)     // 16 tail features handled by threads 0..15

// tanh-approx GELU (|err| vs exact erf-GELU ~5e-4)
__device__ __forceinline__ float gelu_f(float x) {
    float x2    = x * x;
    float inner = fmaf(0.044715f * x, x2, x);
    float e     = exp2f(2.3022082f * inner);          // 2*sqrt(2/pi)*log2(e)
    float r     = __builtin_amdgcn_rcpf(e + 1.0f);
    return fmaf(-x, r, x);                            // x*e/(e+1)
}

__device__ __forceinline__ float4 gelu4(const float4& a) {
    return make_float4(gelu_f(a.x), gelu_f(a.y), gelu_f(a.z), gelu_f(a.w));
}

__device__ __forceinline__ void fma4(float4& a, const float4& h4, float wk) {
    a.x = fmaf(h4.x, wk, a.x);
    a.y = fmaf(h4.y, wk, a.y);
    a.z = fmaf(h4.z, wk, a.z);
    a.w = fmaf(h4.w, wk, a.w);
}

template <int K>
__device__ __forceinline__ void loadIdxW(const int* __restrict__ idx,
                                         const float* __restrict__ w,
                                         int n, int* jc, float* wc) {
    if constexpr (K == 2) {
        int2   j = *(const int2*)(idx + n * 2);
        float2 v = *(const float2*)(w + n * 2);
        jc[0] = j.x; jc[1] = j.y; wc[0] = v.x; wc[1] = v.y;
    } else if constexpr (K == 4) {
        int4   j = *(const int4*)(idx + n * 4);
        float4 v = *(const float4*)(w + n * 4);
        jc[0] = j.x; jc[1] = j.y; jc[2] = j.z; jc[3] = j.w;
        wc[0] = v.x; wc[1] = v.y; wc[2] = v.z; wc[3] = v.w;
    } else {
        int4   ja = *(const int4*)(idx + n * 8);
        int4   jb = *(const int4*)(idx + n * 8 + 4);
        float4 va = *(const float4*)(w + n * 8);
        float4 vb = *(const float4*)(w + n * 8 + 4);
        jc[0] = ja.x; jc[1] = ja.y; jc[2] = ja.z; jc[3] = ja.w;
        jc[4] = jb.x; jc[5] = jb.y; jc[6] = jb.z; jc[7] = jb.w;
        wc[0] = va.x; wc[1] = va.y; wc[2] = va.z; wc[3] = va.w;
        wc[4] = vb.x; wc[5] = vb.y; wc[6] = vb.z; wc[7] = vb.w;
    }
}

// Compute one feature n (both planes) from pre-loaded params.
// Arrays are const-ref + constant-indexed in unrolled loops -> stay in VGPRs.
template <int K>
__device__ __forceinline__ void layer_reg(const float* __restrict__ src,
                                          float* __restrict__ dst,
                                          const int (&jc)[K], const float (&wc)[K],
                                          float bc, int n) {
    float4 lo = make_float4(bc, bc, bc, bc);
    float4 hi = lo;
#pragma unroll
    for (int k = 0; k < K; ++k) {
        const float* g = src + jc[k] * 4;
        fma4(lo, *(const float4*)g, wc[k]);
        fma4(hi, *(const float4*)(g + PL), wc[k]);
    }
    *(float4*)(dst + n * 4)      = gelu4(lo);
    *(float4*)(dst + n * 4 + PL) = gelu4(hi);
}

// Tail variant: loads params per call (only 16 threads; keeps uniform VGPR low)
template <int K>
__device__ __forceinline__ void layer_one(const float* __restrict__ src,
                                          float* __restrict__ dst,
                                          const int* __restrict__ idx,
                                          const float* __restrict__ w,
                                          const float* __restrict__ bias,
                                          int n) {
    int   jc[K];
    float wc[K];
    loadIdxW<K>(idx, w, n, jc, wc);
    layer_reg<K>(src, dst, jc, wc, bias[n], n);
}

__global__ __launch_bounds__(BLOCK)     // NO min-waves arg (r6 lesson: it forced a spill)
void circnn_kernel(const float* __restrict__ x,
                   const int* __restrict__ idx1, const float* __restrict__ w1, const float* __restrict__ b1,
                   const int* __restrict__ idx2, const float* __restrict__ w2, const float* __restrict__ b2,
                   const int* __restrict__ idx3, const float* __restrict__ w3, const float* __restrict__ b3,
                   const float* __restrict__ fcw, const float* __restrict__ fcb,
                   float* __restrict__ out) {
    __shared__ __align__(16) float bufA[D_ * ROWS];   // 25,088 B: x, h2; then FC partials
    __shared__ __align__(16) float bufB[D_ * ROWS];   // 25,088 B: h1, h3
    __shared__ float logits[ROWS * NCLS];             // 320 B

    const int tid  = threadIdx.x;
    const int row0 = blockIdx.x * ROWS;

    // ---- hoisted params for main feature n = tid (issued before x-staging;
    //      L2 latency hides under staging + layer-1 compute). ~31 VGPRs.
    int   j1[2], j2[4], j3[8];
    float v1[2], v2[4], v3[8];
    loadIdxW<2>(idx1, w1, tid, j1, v1);
    loadIdxW<4>(idx2, w2, tid, j2, v2);
    loadIdxW<8>(idx3, w3, tid, j3, v3);
    const float bb1 = b1[tid], bb2 = b2[tid], bb3 = b3[tid];

    // ---- Stage x -> bufA (two-plane): 8 strided-coalesced b32 reads -> 2 b128 writes
    const float* xb = x + (size_t)row0 * D_;
    {
        int n = tid;                      // n < 768 < 784, always valid
        float4 lo, hi;
        lo.x = xb[0 * D_ + n]; lo.y = xb[1 * D_ + n];
        lo.z = xb[2 * D_ + n]; lo.w = xb[3 * D_ + n];
        hi.x = xb[4 * D_ + n]; hi.y = xb[5 * D_ + n];
        hi.z = xb[6 * D_ + n]; hi.w = xb[7 * D_ + n];
        *(float4*)(bufA + n * 4)      = lo;
        *(float4*)(bufA + n * 4 + PL) = hi;
    }
    if (tid < TAIL) {
        int n = BLOCK + tid;
        float4 lo, hi;
        lo.x = xb[0 * D_ + n]; lo.y = xb[1 * D_ + n];
        lo.z = xb[2 * D_ + n]; lo.w = xb[3 * D_ + n];
        hi.x = xb[4 * D_ + n]; hi.y = xb[5 * D_ + n];
        hi.z = xb[6 * D_ + n]; hi.w = xb[7 * D_ + n];
        *(float4*)(bufA + n * 4)      = lo;
        *(float4*)(bufA + n * 4 + PL) = hi;
    }
    __syncthreads();

    // ---- Three sparse layers, ping-pong A->B->A->B, one barrier each
    layer_reg<2>(bufA, bufB, j1, v1, bb1, tid);
    if (tid < TAIL) layer_one<2>(bufA, bufB, idx1, w1, b1, BLOCK + tid);
    __syncthreads();

    layer_reg<4>(bufB, bufA, j2, v2, bb2, tid);
    if (tid < TAIL) layer_one<4>(bufB, bufA, idx2, w2, b2, BLOCK + tid);
    __syncthreads();

    layer_reg<8>(bufA, bufB, j3, v3, bb3, tid);
    if (tid < TAIL) layer_one<8>(bufA, bufB, idx3, w3, b3, BLOCK + tid);
    __syncthreads();

    // ---- FC phase A: 256 threads (4 waves). tid = jj*4 + qq*2 + p:
    //   p  = bit 0     -> 2-way split of the 13 n-chunks (reduced by shfl_xor 1)
    //   qq = bit 1     -> row half (plane)
    //   jj = bits 2..7 -> feature within chunk (0..63)
    // shfl_xor on NAMED members only (r5-proven: no pointer cast -> no spill).
    float4* part4 = (float4*)bufA;    // layout [(jj*2+qq)*NCLSP + c], 22,496 B <= bufA
    if (tid < 256) {
        const int p  = tid & 1;
        const int qq = (tid >> 1) & 1;
        const int jj = tid >> 2;
        float4 facc[NCLS];
#pragma unroll
        for (int c = 0; c < NCLS; ++c) facc[c] = make_float4(0.f, 0.f, 0.f, 0.f);
#pragma unroll 1
        for (int i = p; i < 13; i += 2) {
            int n = jj + (i << 6);
            if (n < D_) {
                float4 hv = *(const float4*)(bufB + qq * PL + n * 4);
#pragma unroll
                for (int c = 0; c < NCLS; ++c)
                    fma4(facc[c], hv, fcw[c * D_ + n]);
            }
        }
#pragma unroll
        for (int c = 0; c < NCLS; ++c) {
            facc[c].x += __shfl_xor(facc[c].x, 1);
            facc[c].y += __shfl_xor(facc[c].y, 1);
            facc[c].z += __shfl_xor(facc[c].z, 1);
            facc[c].w += __shfl_xor(facc[c].w, 1);
        }
        if (p == 0) {
#pragma unroll
            for (int c = 0; c < NCLS; ++c)
                part4[(jj * 2 + qq) * NCLSP + c] = facc[c];
        }
    }
    __syncthreads();

    // ---- FC phase B: 80 threads (r, c) sum 64 jj-partials -> logits
    if (tid < ROWS * NCLS) {
        int r = tid / NCLS, c = tid - r * NCLS;
        int qq = r >> 2, comp = r & 3;
        const float* pf = (const float*)part4;
        float s = fcb[c];
#pragma unroll 4
        for (int jj = 0; jj < 64; ++jj)
            s += pf[((jj * 2 + qq) * NCLSP + c) * 4 + comp];
        logits[tid] = s;
    }
    __syncthreads();

    // ---- softmax (redundant per-(r,c) thread), coalesced 80-float store
    if (tid < ROWS * NCLS) {
        int r = tid / NCLS;
        const float* lg = logits + r * NCLS;
        float m = lg[0];
#pragma unroll
        for (int c = 1; c < NCLS; ++c) m = fmaxf(m, lg[c]);
        float s = 0.f;
#pragma unroll
        for (int c = 0; c < NCLS; ++c) s += __expf(lg[c] - m);
        out[(size_t)row0 * NCLS + tid] = __expf(logits[tid] - m) / s;
    }
}

extern "C" void kernel_launch(void* const* d_in, const int* in_sizes, int n_in,
                              void* d_out, int out_size, void* d_ws, size_t ws_size,
                              hipStream_t stream) {
    const float* x    = (const float*)d_in[0];
    const int*   idx1 = (const int*)d_in[1];
    const float* w1   = (const float*)d_in[2];
    const float* b1   = (const float*)d_in[3];
    const int*   idx2 = (const int*)d_in[4];
    const float* w2   = (const float*)d_in[5];
    const float* b2   = (const float*)d_in[6];
    const int*   idx3 = (const int*)d_in[7];
    const float* w3   = (const float*)d_in[8];
    const float* b3   = (const float*)d_in[9];
    const float* fcw  = (const float*)d_in[10];
    const float* fcb  = (const float*)d_in[11];
    float* out = (float*)d_out;

    circnn_kernel<<<dim3(NB), dim3(BLOCK), 0, stream>>>(
        x, idx1, w1, b1, idx2, w2, b2, idx3, w3, b3, fcw, fcb, out);
}

// Round 9
// 427.941 us; speedup vs baseline: 2.3117x; 1.3179x over previous
//
#include <hip/hip_runtime.h>

#define D_     784
#define ROWS   8
#define NCLS   10
#define BLOCK  768              // 12 waves; 2 blocks/CU (proven best residency shape)
#define NB     (65536 / ROWS)   // 8192 blocks
#define PL     (D_ * 4)         // floats per LDS plane (3136): plane0 = rows 0-3, plane1 = rows 4-7
#define TAIL   (D_ - BLOCK)     // 16 tail features handled by threads 0..15

// tanh-approx GELU (|err| vs exact erf-GELU ~5e-4)
__device__ __forceinline__ float gelu_f(float x) {
    float x2    = x * x;
    float inner = fmaf(0.044715f * x, x2, x);
    float e     = exp2f(2.3022082f * inner);          // 2*sqrt(2/pi)*log2(e)
    float r     = __builtin_amdgcn_rcpf(e + 1.0f);
    return fmaf(-x, r, x);                            // x*e/(e+1)
}

__device__ __forceinline__ float4 gelu4(const float4& a) {
    return make_float4(gelu_f(a.x), gelu_f(a.y), gelu_f(a.z), gelu_f(a.w));
}

__device__ __forceinline__ void fma4(float4& a, const float4& h4, float wk) {
    a.x = fmaf(h4.x, wk, a.x);
    a.y = fmaf(h4.y, wk, a.y);
    a.z = fmaf(h4.z, wk, a.z);
    a.w = fmaf(h4.w, wk, a.w);
}

template <int K>
__device__ __forceinline__ void loadIdxW(const int* __restrict__ idx,
                                         const float* __restrict__ w,
                                         int n, int* jc, float* wc) {
    if constexpr (K == 2) {
        int2   j = *(const int2*)(idx + n * 2);
        float2 v = *(const float2*)(w + n * 2);
        jc[0] = j.x; jc[1] = j.y; wc[0] = v.x; wc[1] = v.y;
    } else if constexpr (K == 4) {
        int4   j = *(const int4*)(idx + n * 4);
        float4 v = *(const float4*)(w + n * 4);
        jc[0] = j.x; jc[1] = j.y; jc[2] = j.z; jc[3] = j.w;
        wc[0] = v.x; wc[1] = v.y; wc[2] = v.z; wc[3] = v.w;
    } else {
        int4   ja = *(const int4*)(idx + n * 8);
        int4   jb = *(const int4*)(idx + n * 8 + 4);
        float4 va = *(const float4*)(w + n * 8);
        float4 vb = *(const float4*)(w + n * 8 + 4);
        jc[0] = ja.x; jc[1] = ja.y; jc[2] = ja.z; jc[3] = ja.w;
        jc[4] = jb.x; jc[5] = jb.y; jc[6] = jb.z; jc[7] = jb.w;
        wc[0] = va.x; wc[1] = va.y; wc[2] = va.z; wc[3] = va.w;
        wc[4] = vb.x; wc[5] = vb.y; wc[6] = vb.z; wc[7] = vb.w;
    }
}

// One feature n, all 8 rows. src/dst are two-plane LDS buffers:
// plane0 (rows 0-3) at [n*4], plane1 (rows 4-7) at [n*4 + PL] (ds offset imm 12544 B).
// Flat, fully unrolled. Params loaded per phase (r8 lesson: hoisting them across
// barriers pins 31 regs and starves the gather pipeline).
template <int K>
__device__ __forceinline__ void layer_one(const float* __restrict__ src,
                                          float* __restrict__ dst,
                                          const int* __restrict__ idx,
                                          const float* __restrict__ w,
                                          const float* __restrict__ bias,
                                          int n) {
    int   jc[K];
    float wc[K];
    loadIdxW<K>(idx, w, n, jc, wc);
    float  bc = bias[n];
    float4 lo = make_float4(bc, bc, bc, bc);
    float4 hi = lo;
#pragma unroll
    for (int k = 0; k < K; ++k) {
        const float* g = src + jc[k] * 4;
        float4 gl = *(const float4*)g;          // plane0
        float4 gh = *(const float4*)(g + PL);   // plane1, folded imm offset
        fma4(lo, gl, wc[k]);
        fma4(hi, gh, wc[k]);
    }
    *(float4*)(dst + n * 4)      = gelu4(lo);
    *(float4*)(dst + n * 4 + PL) = gelu4(hi);
}

// (BLOCK, 6): 6 waves/EU = 24 waves/CU = the 2-block residency we already have,
// but raises the VGPR cap 64 -> 85 so the scheduler can keep ~8 ds_read_b128
// gathers in flight instead of ~2 (r2/r8 evidence: 40-44 VGPR = pipeline-starved).
__global__ __launch_bounds__(BLOCK, 6)
void circnn_kernel(const float* __restrict__ x,
                   const int* __restrict__ idx1, const float* __restrict__ w1, const float* __restrict__ b1,
                   const int* __restrict__ idx2, const float* __restrict__ w2, const float* __restrict__ b2,
                   const int* __restrict__ idx3, const float* __restrict__ w3, const float* __restrict__ b3,
                   const float* __restrict__ fcw, const float* __restrict__ fcb,
                   float* __restrict__ out) {
    __shared__ __align__(16) float bufA[D_ * ROWS];   // 25,088 B: x, h2; then FC partials
    __shared__ __align__(16) float bufB[D_ * ROWS];   // 25,088 B: h1, h3
    __shared__ float logits[ROWS * NCLS];             // 320 B

    const int tid  = threadIdx.x;
    const int row0 = blockIdx.x * ROWS;

    // ---- Stage x -> bufA (two-plane): 8 strided-coalesced b32 reads -> 2 b128 writes
    const float* xb = x + (size_t)row0 * D_;
    {
        int n = tid;                      // n < 768 < 784, always valid
        float4 lo, hi;
        lo.x = xb[0 * D_ + n]; lo.y = xb[1 * D_ + n];
        lo.z = xb[2 * D_ + n]; lo.w = xb[3 * D_ + n];
        hi.x = xb[4 * D_ + n]; hi.y = xb[5 * D_ + n];
        hi.z = xb[6 * D_ + n]; hi.w = xb[7 * D_ + n];
        *(float4*)(bufA + n * 4)      = lo;
        *(float4*)(bufA + n * 4 + PL) = hi;
    }
    if (tid < TAIL) {
        int n = BLOCK + tid;
        float4 lo, hi;
        lo.x = xb[0 * D_ + n]; lo.y = xb[1 * D_ + n];
        lo.z = xb[2 * D_ + n]; lo.w = xb[3 * D_ + n];
        hi.x = xb[4 * D_ + n]; hi.y = xb[5 * D_ + n];
        hi.z = xb[6 * D_ + n]; hi.w = xb[7 * D_ + n];
        *(float4*)(bufA + n * 4)      = lo;
        *(float4*)(bufA + n * 4 + PL) = hi;
    }
    __syncthreads();

    // ---- Three sparse layers, ping-pong A->B->A->B, one barrier each
    layer_one<2>(bufA, bufB, idx1, w1, b1, tid);
    if (tid < TAIL) layer_one<2>(bufA, bufB, idx1, w1, b1, BLOCK + tid);
    __syncthreads();

    layer_one<4>(bufB, bufA, idx2, w2, b2, tid);
    if (tid < TAIL) layer_one<4>(bufB, bufA, idx2, w2, b2, BLOCK + tid);
    __syncthreads();

    layer_one<8>(bufA, bufB, idx3, w3, b3, tid);
    if (tid < TAIL) layer_one<8>(bufA, bufB, idx3, w3, b3, BLOCK + tid);
    __syncthreads();

    // ---- FC phase A: 128 threads, partials into bufA (free).
    // facc stays in registers (member access only — NO pointer casts, no shuffles).
    float4* part4 = (float4*)bufA;    // layout [(jj*2+qq)*NCLS + c], 20,480 B
    if (tid < 128) {
        const int jj = tid >> 1;      // 0..63
        const int qq = tid & 1;       // row half (plane)
        float4 facc[NCLS];
#pragma unroll
        for (int c = 0; c < NCLS; ++c) facc[c] = make_float4(0.f, 0.f, 0.f, 0.f);
#pragma unroll 1
        for (int i = 0; i < 13; ++i) {
            int n = jj + 64 * i;
            if (n < D_) {
                float4 hv = *(const float4*)(bufB + qq * PL + n * 4);
#pragma unroll
                for (int c = 0; c < NCLS; ++c)
                    fma4(facc[c], hv, fcw[c * D_ + n]);
            }
        }
#pragma unroll
        for (int c = 0; c < NCLS; ++c)
            part4[(jj * 2 + qq) * NCLS + c] = facc[c];
    }
    __syncthreads();

    // ---- FC phase B: 80 threads (r, c) sum 64 jj-partials -> logits
    if (tid < ROWS * NCLS) {
        int r = tid / NCLS, c = tid - r * NCLS;
        int qq = r >> 2, comp = r & 3;
        const float* pf = (const float*)part4;
        float s = fcb[c];
#pragma unroll 4
        for (int jj = 0; jj < 64; ++jj)
            s += pf[((jj * 2 + qq) * NCLS + c) * 4 + comp];
        logits[tid] = s;
    }
    __syncthreads();

    // ---- softmax (redundant per-(r,c) thread), coalesced 80-float store
    if (tid < ROWS * NCLS) {
        int r = tid / NCLS;
        const float* lg = logits + r * NCLS;
        float m = lg[0];
#pragma unroll
        for (int c = 1; c < NCLS; ++c) m = fmaxf(m, lg[c]);
        float s = 0.f;
#pragma unroll
        for (int c = 0; c < NCLS; ++c) s += __expf(lg[c] - m);
        out[(size_t)row0 * NCLS + tid] = __expf(logits[tid] - m) / s;
    }
}

extern "C" void kernel_launch(void* const* d_in, const int* in_sizes, int n_in,
                              void* d_out, int out_size, void* d_ws, size_t ws_size,
                              hipStream_t stream) {
    const float* x    = (const float*)d_in[0];
    const int*   idx1 = (const int*)d_in[1];
    const float* w1   = (const float*)d_in[2];
    const float* b1   = (const float*)d_in[3];
    const int*   idx2 = (const int*)d_in[4];
    const float* w2   = (const float*)d_in[5];
    const float* b2   = (const float*)d_in[6];
    const int*   idx3 = (const int*)d_in[7];
    const float* w3   = (const float*)d_in[8];
    const float* b3   = (const float*)d_in[9];
    const float* fcw  = (const float*)d_in[10];
    const float* fcb  = (const float*)d_in[11];
    float* out = (float*)d_out;

    circnn_kernel<<<dim3(NB), dim3(BLOCK), 0, stream>>>(
        x, idx1, w1, b1, idx2, w2, b2, idx3, w3, b3, fcw, fcb, out);
}